// Round 1
// baseline (3070.288 us; speedup 1.0000x reference)
//
#include <hip/hip_runtime.h>
#include <hip/hip_bf16.h>
#include <math.h>
#include <stdint.h>

#define T_TOK 32768
#define H_DIM 768
#define I_DIM 3072
#define E_NUM 8
#define PADROWS (T_TOK * 2 + E_NUM * 64)  /* 66048 */
#define NTILEX (PADROWS / 64)             /* 1032 */

typedef __attribute__((ext_vector_type(8))) __bf16 bf16x8;
typedef __attribute__((ext_vector_type(4))) float floatx4;

__device__ inline __bf16 f2bf(float f) { return (__bf16)f; }

__device__ inline float gelu_exact(float v) {
    return 0.5f * v * (1.f + erff(v * 0.70710678118654752f));
}

// ---------------- router ----------------
__global__ __launch_bounds__(256) void router_kernel(
    const float* __restrict__ x, const float* __restrict__ gw,
    float* __restrict__ logits, int* __restrict__ tok_sel,
    float* __restrict__ tok_w, int* __restrict__ cnt)
{
    __shared__ float sgw[E_NUM * H_DIM];
    __shared__ int lcnt[E_NUM];
    int tid = threadIdx.x;
    for (int i = tid; i < E_NUM * H_DIM; i += 256) sgw[i] = gw[i];
    if (tid < E_NUM) lcnt[tid] = 0;
    __syncthreads();

    int t = blockIdx.x * 256 + tid;
    const float* xr = x + (size_t)t * H_DIM;
    float acc[E_NUM];
#pragma unroll
    for (int e = 0; e < E_NUM; e++) acc[e] = 0.f;
    for (int k = 0; k < H_DIM; k += 4) {
        float4 xv = *(const float4*)(xr + k);
#pragma unroll
        for (int e = 0; e < E_NUM; e++) {
            const float* g = &sgw[e * H_DIM + k];
            acc[e] += xv.x * g[0] + xv.y * g[1] + xv.z * g[2] + xv.w * g[3];
        }
    }
#pragma unroll
    for (int e = 0; e < E_NUM; e++) logits[(size_t)t * E_NUM + e] = acc[e];

    // top-2, first-occurrence tie-break (matches jax.lax.top_k)
    int e1 = 0; float v1 = acc[0];
#pragma unroll
    for (int e = 1; e < E_NUM; e++) if (acc[e] > v1) { v1 = acc[e]; e1 = e; }
    int e2 = (e1 == 0) ? 1 : 0; float v2 = acc[(e1 == 0) ? 1 : 0];
#pragma unroll
    for (int e = 0; e < E_NUM; e++)
        if (e != e1 && acc[e] > v2) { v2 = acc[e]; e2 = e; }

    // renormalized top-2 softmax weights: softmax denominator cancels
    float p2 = expf(v2 - v1);
    float s = 1.f + p2;
    tok_sel[2 * t] = e1; tok_sel[2 * t + 1] = e2;
    tok_w[2 * t] = 1.f / s; tok_w[2 * t + 1] = p2 / s;

    atomicAdd(&lcnt[e1], 1); atomicAdd(&lcnt[e2], 1);
    __syncthreads();
    if (tid < E_NUM) atomicAdd(&cnt[tid], lcnt[tid]);
}

// ---------------- scan (offsets, padded to 64 rows per expert) ----------------
__global__ void scan_kernel(const int* __restrict__ cnt, int* __restrict__ off)
{
    if (threadIdx.x == 0 && blockIdx.x == 0) {
        int o = 0;
        for (int e = 0; e < E_NUM; e++) {
            off[e] = o;
            o += (cnt[e] + 63) & ~63;
        }
        off[E_NUM] = o;
    }
}

// ---------------- scatter pairs into expert-grouped compact array ----------------
__global__ __launch_bounds__(256) void scatter_kernel(
    const int* __restrict__ tok_sel, const float* __restrict__ tok_w,
    const int* __restrict__ off, int* __restrict__ fill,
    int* __restrict__ pair_token, float* __restrict__ pair_w)
{
    __shared__ int lcnt[E_NUM];
    __shared__ int base[E_NUM];
    int tid = threadIdx.x;
    if (tid < E_NUM) lcnt[tid] = 0;
    __syncthreads();
    int t = blockIdx.x * 256 + tid;
    int e1 = tok_sel[2 * t], e2 = tok_sel[2 * t + 1];
    int lp1 = atomicAdd(&lcnt[e1], 1);
    int lp2 = atomicAdd(&lcnt[e2], 1);
    __syncthreads();
    if (tid < E_NUM) base[tid] = (lcnt[tid] > 0) ? atomicAdd(&fill[tid], lcnt[tid]) : 0;
    __syncthreads();
    int p1 = off[e1] + base[e1] + lp1;
    int p2 = off[e2] + base[e2] + lp2;
    pair_token[p1] = t; pair_w[p1] = tok_w[2 * t];
    pair_token[p2] = t; pair_w[p2] = tok_w[2 * t + 1];
}

// ---------------- pass 1: hmid = gelu(X @ w1 + b1), bf16 out ----------------
__global__ __launch_bounds__(256) void moe_gemm1(
    const float* __restrict__ x, const float* __restrict__ w1,
    const float* __restrict__ b1, const int* __restrict__ off_g,
    const int* __restrict__ pair_token, __bf16* __restrict__ hmid,
    int chunk_base, int chunkI)
{
    __shared__ __align__(16) __bf16 Bt[64][40];  // [n][k], +8 pad keeps 16B rows
    int m0 = blockIdx.x * 64;
    if (m0 >= off_g[E_NUM]) return;
    int e = 0;
#pragma unroll
    for (int k = 0; k < E_NUM; k++) if (m0 >= off_g[k + 1]) e = k + 1;

    int tid = threadIdx.x;
    int w = tid >> 6;
    int lane = tid & 63;
    int ln = lane & 15;
    int q = lane >> 4;
    int i0 = chunk_base + blockIdx.y * 64;

    int rowA = m0 + w * 16 + ln;
    int tokA = pair_token[rowA];
    const float* xrow = (tokA >= 0) ? (x + (size_t)tokA * H_DIM) : x;

    floatx4 acc[4];
#pragma unroll
    for (int nt = 0; nt < 4; nt++) acc[nt] = (floatx4){0.f, 0.f, 0.f, 0.f};

    int n = tid & 63;
    int kg = tid >> 6;
    for (int kk = 0; kk < H_DIM; kk += 32) {
        __syncthreads();
        {
            const float* wp = w1 + ((size_t)e * H_DIM + kk + kg * 8) * I_DIM + i0 + n;
            bf16x8 tmp;
#pragma unroll
            for (int j = 0; j < 8; j++) tmp[j] = f2bf(wp[(size_t)j * I_DIM]);
            *(bf16x8*)&Bt[n][kg * 8] = tmp;
        }
        __syncthreads();
        bf16x8 a;
        if (tokA >= 0) {
            const float4* ap = (const float4*)(xrow + kk + q * 8);
            float4 u = ap[0], v = ap[1];
            a[0] = f2bf(u.x); a[1] = f2bf(u.y); a[2] = f2bf(u.z); a[3] = f2bf(u.w);
            a[4] = f2bf(v.x); a[5] = f2bf(v.y); a[6] = f2bf(v.z); a[7] = f2bf(v.w);
        } else {
#pragma unroll
            for (int j = 0; j < 8; j++) a[j] = (__bf16)0.f;
        }
#pragma unroll
        for (int nt = 0; nt < 4; nt++) {
            bf16x8 b = *(bf16x8*)&Bt[nt * 16 + ln][q * 8];
            acc[nt] = __builtin_amdgcn_mfma_f32_16x16x32_bf16(a, b, acc[nt], 0, 0, 0);
        }
    }

#pragma unroll
    for (int nt = 0; nt < 4; nt++) {
        int colg = i0 + nt * 16 + ln;      // global I index
        int coll = colg - chunk_base;      // local col within chunk
        float bv = b1[e * I_DIM + colg];
#pragma unroll
        for (int r = 0; r < 4; r++) {
            int rowg = m0 + w * 16 + q * 4 + r;
            float v = acc[nt][r] + bv;
            hmid[(size_t)rowg * chunkI + coll] = f2bf(gelu_exact(v));
        }
    }
}

// ---------------- pass 2: out[token] += pw * (hmid @ w2 + b2) ----------------
__global__ __launch_bounds__(256) void moe_gemm2(
    const __bf16* __restrict__ hmid, const float* __restrict__ w2,
    const float* __restrict__ b2, const int* __restrict__ off_g,
    const int* __restrict__ pair_token, const float* __restrict__ pair_w,
    float* __restrict__ out, int chunk_base, int chunkI)
{
    __shared__ __align__(16) __bf16 Bt[64][40];
    int m0 = blockIdx.x * 64;
    if (m0 >= off_g[E_NUM]) return;
    int e = 0;
#pragma unroll
    for (int k = 0; k < E_NUM; k++) if (m0 >= off_g[k + 1]) e = k + 1;

    int tid = threadIdx.x;
    int w = tid >> 6;
    int lane = tid & 63;
    int ln = lane & 15;
    int q = lane >> 4;
    int h0 = blockIdx.y * 64;

    int rowA = m0 + w * 16 + ln;
    const __bf16* arow = hmid + (size_t)rowA * chunkI;

    floatx4 acc[4];
#pragma unroll
    for (int nt = 0; nt < 4; nt++) acc[nt] = (floatx4){0.f, 0.f, 0.f, 0.f};

    int n = tid & 63;
    int kg = tid >> 6;
    for (int kk = 0; kk < chunkI; kk += 32) {
        __syncthreads();
        {
            const float* wp = w2 + ((size_t)e * I_DIM + chunk_base + kk + kg * 8) * H_DIM + h0 + n;
            bf16x8 tmp;
#pragma unroll
            for (int j = 0; j < 8; j++) tmp[j] = f2bf(wp[(size_t)j * H_DIM]);
            *(bf16x8*)&Bt[n][kg * 8] = tmp;
        }
        __syncthreads();
        bf16x8 a = *(const bf16x8*)(arow + kk + q * 8);
#pragma unroll
        for (int nt = 0; nt < 4; nt++) {
            bf16x8 b = *(bf16x8*)&Bt[nt * 16 + ln][q * 8];
            acc[nt] = __builtin_amdgcn_mfma_f32_16x16x32_bf16(a, b, acc[nt], 0, 0, 0);
        }
    }

#pragma unroll
    for (int r = 0; r < 4; r++) {
        int rowg = m0 + w * 16 + q * 4 + r;
        int tok = pair_token[rowg];
        if (tok < 0) continue;
        float pw = pair_w[rowg];
#pragma unroll
        for (int nt = 0; nt < 4; nt++) {
            int col = h0 + nt * 16 + ln;
            float v = (acc[nt][r] + b2[e * H_DIM + col]) * pw;
            atomicAdd(&out[(size_t)tok * H_DIM + col], v);
        }
    }
}

extern "C" void kernel_launch(void* const* d_in, const int* in_sizes, int n_in,
                              void* d_out, int out_size, void* d_ws, size_t ws_size,
                              hipStream_t stream)
{
    const float* x  = (const float*)d_in[0];
    const float* gw = (const float*)d_in[1];
    const float* w1 = (const float*)d_in[2];
    const float* b1 = (const float*)d_in[3];
    const float* w2 = (const float*)d_in[4];
    const float* b2 = (const float*)d_in[5];
    float* out = (float*)d_out;
    float* logits = out + (size_t)T_TOK * H_DIM;

    // workspace carve
    char* p0 = (char*)d_ws;
    char* p = p0;
    int* cnt  = (int*)p; p += 32;
    int* fill = (int*)p; p += 32;
    int* off  = (int*)p; p += 64;
    int* tok_sel = (int*)p;  p += (size_t)2 * T_TOK * 4;
    float* tok_w = (float*)p; p += (size_t)2 * T_TOK * 4;
    int* pair_token = (int*)p;  p += (size_t)PADROWS * 4;
    float* pair_w   = (float*)p; p += (size_t)PADROWS * 4;
    p = (char*)(((uintptr_t)p + 255) & ~(uintptr_t)255);
    __bf16* hmid = (__bf16*)p;
    size_t used = (size_t)(p - p0);
    size_t avail = (ws_size > used) ? ws_size - used : 0;

    // choose largest I-chunk whose hmid buffer fits in the workspace
    static const int cdivs[] = {1, 2, 3, 4, 6, 8, 12, 16, 24, 48};
    int chunkI = 64;
    for (int i = 0; i < 10; i++) {
        int ci = I_DIM / cdivs[i];
        if ((size_t)PADROWS * (size_t)ci * 2 <= avail) { chunkI = ci; break; }
    }

    hipMemsetAsync(out, 0, (size_t)T_TOK * H_DIM * sizeof(float), stream);
    hipMemsetAsync(cnt, 0, 128, stream);                       // cnt + fill + off
    hipMemsetAsync(pair_token, 0xFF, (size_t)PADROWS * 4, stream);  // -1 = pad row

    router_kernel<<<T_TOK / 256, 256, 0, stream>>>(x, gw, logits, tok_sel, tok_w, cnt);
    scan_kernel<<<1, 64, 0, stream>>>(cnt, off);
    scatter_kernel<<<T_TOK / 256, 256, 0, stream>>>(tok_sel, tok_w, off, fill,
                                                    pair_token, pair_w);

    for (int cb = 0; cb < I_DIM; cb += chunkI) {
        moe_gemm1<<<dim3(NTILEX, chunkI / 64), 256, 0, stream>>>(
            x, w1, b1, off, pair_token, hmid, cb, chunkI);
        moe_gemm2<<<dim3(NTILEX, H_DIM / 64), 256, 0, stream>>>(
            hmid, w2, b2, off, pair_token, pair_w, out, cb, chunkI);
    }
}

// Round 2
// 1698.393 us; speedup vs baseline: 1.8078x; 1.8078x over previous
//
#include <hip/hip_runtime.h>
#include <hip/hip_bf16.h>
#include <math.h>
#include <stdint.h>

#define T_TOK 32768
#define H_DIM 768
#define I_DIM 3072
#define E_NUM 8
#define PADROWS 66560              /* 2*T + 8*128, 128-aligned expert regions */
#define NTILE   520                /* PADROWS / 128 */

typedef __attribute__((ext_vector_type(8))) __bf16 bf16x8;
typedef __attribute__((ext_vector_type(4))) float floatx4;

__device__ inline __bf16 f2bf(float f) { return (__bf16)f; }
__device__ inline unsigned short f2bfu(float f) {
    __bf16 b = (__bf16)f; return *(unsigned short*)&b;
}

// async global->LDS, 16B per lane; LDS dest = wave-uniform base + lane*16,
// global address is per-lane (gather-capable).
__device__ inline void g2lds16(const void* g, void* l) {
    __builtin_amdgcn_global_load_lds(
        (const __attribute__((address_space(1))) unsigned int*)g,
        (__attribute__((address_space(3))) unsigned int*)l, 16, 0, 0);
}

// gelu tanh-form: 0.5x(1+tanh(t)) == x / (1 + exp(-2t)), t = 0.79788x + 0.035677x^3
__device__ inline float gelu_fast(float x) {
    float x2 = x * x;
    float t = x * (0.7978845608f + 0.0356774081f * x2);
    float e = __expf(-2.f * t);
    return x / (1.f + e);
}

// ---------------- router ----------------
__global__ __launch_bounds__(256) void router_kernel(
    const float* __restrict__ x, const float* __restrict__ gw,
    float* __restrict__ logits, int* __restrict__ tok_sel,
    float* __restrict__ tok_w, int* __restrict__ cnt)
{
    __shared__ float sgw[E_NUM * H_DIM];
    __shared__ int lcnt[E_NUM];
    int tid = threadIdx.x;
    for (int i = tid; i < E_NUM * H_DIM; i += 256) sgw[i] = gw[i];
    if (tid < E_NUM) lcnt[tid] = 0;
    __syncthreads();

    int t = blockIdx.x * 256 + tid;
    const float* xr = x + (size_t)t * H_DIM;
    float acc[E_NUM];
#pragma unroll
    for (int e = 0; e < E_NUM; e++) acc[e] = 0.f;
    for (int k = 0; k < H_DIM; k += 4) {
        float4 xv = *(const float4*)(xr + k);
#pragma unroll
        for (int e = 0; e < E_NUM; e++) {
            const float* g = &sgw[e * H_DIM + k];
            acc[e] += xv.x * g[0] + xv.y * g[1] + xv.z * g[2] + xv.w * g[3];
        }
    }
#pragma unroll
    for (int e = 0; e < E_NUM; e++) logits[(size_t)t * E_NUM + e] = acc[e];

    int e1 = 0; float v1 = acc[0];
#pragma unroll
    for (int e = 1; e < E_NUM; e++) if (acc[e] > v1) { v1 = acc[e]; e1 = e; }
    int e2 = (e1 == 0) ? 1 : 0; float v2 = acc[(e1 == 0) ? 1 : 0];
#pragma unroll
    for (int e = 0; e < E_NUM; e++)
        if (e != e1 && acc[e] > v2) { v2 = acc[e]; e2 = e; }

    float p2 = expf(v2 - v1);
    float s = 1.f + p2;
    tok_sel[2 * t] = e1; tok_sel[2 * t + 1] = e2;
    tok_w[2 * t] = 1.f / s; tok_w[2 * t + 1] = p2 / s;

    atomicAdd(&lcnt[e1], 1); atomicAdd(&lcnt[e2], 1);
    __syncthreads();
    if (tid < E_NUM) atomicAdd(&cnt[tid], lcnt[tid]);
}

// ---------------- scan: 128-aligned expert offsets ----------------
__global__ void scan_kernel(const int* __restrict__ cnt, int* __restrict__ off)
{
    if (threadIdx.x == 0 && blockIdx.x == 0) {
        int o = 0;
        for (int e = 0; e < E_NUM; e++) {
            off[e] = o;
            o += (cnt[e] + 127) & ~127;
        }
        off[E_NUM] = o;
    }
}

// ---------------- scatter pairs into expert-grouped compact array ----------------
__global__ __launch_bounds__(256) void scatter_kernel(
    const int* __restrict__ tok_sel, const float* __restrict__ tok_w,
    const int* __restrict__ off, int* __restrict__ fill,
    int* __restrict__ pair_token, float* __restrict__ pair_w)
{
    __shared__ int lcnt[E_NUM];
    __shared__ int base[E_NUM];
    int tid = threadIdx.x;
    if (tid < E_NUM) lcnt[tid] = 0;
    __syncthreads();
    int t = blockIdx.x * 256 + tid;
    int e1 = tok_sel[2 * t], e2 = tok_sel[2 * t + 1];
    int lp1 = atomicAdd(&lcnt[e1], 1);
    int lp2 = atomicAdd(&lcnt[e2], 1);
    __syncthreads();
    if (tid < E_NUM) base[tid] = (lcnt[tid] > 0) ? atomicAdd(&fill[tid], lcnt[tid]) : 0;
    __syncthreads();
    int p1 = off[e1] + base[e1] + lp1;
    int p2 = off[e2] + base[e2] + lp2;
    pair_token[p1] = t; pair_w[p1] = tok_w[2 * t];
    pair_token[p2] = t; pair_w[p2] = tok_w[2 * t + 1];
}

// ---------------- x fp32 -> bf16 ----------------
__global__ __launch_bounds__(256) void convert_x(
    const float* __restrict__ x, __bf16* __restrict__ xb)
{
    int i = blockIdx.x * 256 + threadIdx.x;      // i indexes groups of 8
    float4 a = ((const float4*)x)[2 * i];
    float4 b = ((const float4*)x)[2 * i + 1];
    bf16x8 o;
    o[0] = f2bf(a.x); o[1] = f2bf(a.y); o[2] = f2bf(a.z); o[3] = f2bf(a.w);
    o[4] = f2bf(b.x); o[5] = f2bf(b.y); o[6] = f2bf(b.z); o[7] = f2bf(b.w);
    ((bf16x8*)xb)[i] = o;
}

// ---------------- W (E,R,C) fp32 -> Wt (E,C,R) bf16, LDS tile transpose ----------------
__global__ __launch_bounds__(256) void transpose_w(
    const float* __restrict__ W, __bf16* __restrict__ Wt, int R, int C)
{
    __shared__ unsigned short T[64][66];   // +2 pad: column reads conflict-free-ish
    int e = blockIdx.z;
    int r0 = blockIdx.y * 64, c0 = blockIdx.x * 64;
    const float* Wp = W + (size_t)e * R * C;
    __bf16* Wtp = Wt + (size_t)e * C * R;
    int tid = threadIdx.x;

    int rl = tid >> 2, cg = tid & 3;       // 64 rows x 4 col-groups of 16
    const float* src = Wp + (size_t)(r0 + rl) * C + c0 + cg * 16;
#pragma unroll
    for (int u = 0; u < 4; u++) {
        float4 v = *(const float4*)(src + u * 4);
        unsigned p0 = (unsigned)f2bfu(v.x) | ((unsigned)f2bfu(v.y) << 16);
        unsigned p1 = (unsigned)f2bfu(v.z) | ((unsigned)f2bfu(v.w) << 16);
        *(unsigned*)&T[rl][cg * 16 + u * 4]     = p0;
        *(unsigned*)&T[rl][cg * 16 + u * 4 + 2] = p1;
    }
    __syncthreads();

    int cl = tid >> 2, rg = tid & 3;       // 64 out-rows x 4 r-groups of 16
    __bf16* dst = Wtp + (size_t)(c0 + cl) * R + r0 + rg * 16;
#pragma unroll
    for (int half = 0; half < 2; half++) {
        bf16x8 o;
#pragma unroll
        for (int j = 0; j < 8; j++) {
            unsigned short b = T[rg * 16 + half * 8 + j][cl];
            o[j] = *(__bf16*)&b;
        }
        *(bf16x8*)(dst + half * 8) = o;
    }
}

// ---------------- pass 1: hmid = gelu(X @ W1 + b1), 128x128 tile ----------------
__global__ __launch_bounds__(256) void moe_gemm1(
    const __bf16* __restrict__ xbf, const __bf16* __restrict__ w1t,
    const float* __restrict__ b1, const int* __restrict__ off_g,
    const int* __restrict__ pair_token, __bf16* __restrict__ hmid,
    int chunk_base, int chunkI)
{
    __shared__ __align__(16) __bf16 As[128][32];
    __shared__ __align__(16) __bf16 Bs[128][32];
    int m0 = blockIdx.x * 128;
    if (m0 >= off_g[E_NUM]) return;
    int e = 0;
#pragma unroll
    for (int k = 0; k < E_NUM - 1; k++) if (m0 >= off_g[k + 1]) e = k + 1;

    int tid = threadIdx.x;
    int w = tid >> 6, lane = tid & 63;
    int ln = lane & 15, q = lane >> 4;
    int wm = w >> 1, wn = w & 1;
    int sub = lane >> 2, kp = lane & 3;
    int i0 = chunk_base + blockIdx.y * 128;

    // gathered A staging pointers (per-lane global addr; pad rows -> token 0)
    int rA0 = m0 + w * 32 + sub;
    int t0 = pair_token[rA0]; if (t0 < 0) t0 = 0;
    int t1 = pair_token[rA0 + 16]; if (t1 < 0) t1 = 0;
    const __bf16* gA0 = xbf + (size_t)t0 * H_DIM + kp * 8;
    const __bf16* gA1 = xbf + (size_t)t1 * H_DIM + kp * 8;
    const __bf16* gB0 = w1t + ((size_t)e * I_DIM + i0 + w * 32 + sub) * H_DIM + kp * 8;
    const __bf16* gB1 = gB0 + (size_t)16 * H_DIM;
    void* lA0 = &As[w * 32][0];
    void* lA1 = &As[w * 32 + 16][0];
    void* lB0 = &Bs[w * 32][0];
    void* lB1 = &Bs[w * 32 + 16][0];

    floatx4 acc[4][4];
#pragma unroll
    for (int a = 0; a < 4; a++)
#pragma unroll
        for (int b = 0; b < 4; b++) acc[a][b] = (floatx4){0.f, 0.f, 0.f, 0.f};

    for (int kk = 0; kk < H_DIM; kk += 32) {
        __syncthreads();
        g2lds16(gA0 + kk, lA0);
        g2lds16(gA1 + kk, lA1);
        g2lds16(gB0 + kk, lB0);
        g2lds16(gB1 + kk, lB1);
        __syncthreads();   // compiler emits s_waitcnt vmcnt(0) before s_barrier
        bf16x8 af[4], bfr[4];
#pragma unroll
        for (int mt = 0; mt < 4; mt++) af[mt] = *(bf16x8*)&As[wm * 64 + mt * 16 + ln][q * 8];
#pragma unroll
        for (int nt = 0; nt < 4; nt++) bfr[nt] = *(bf16x8*)&Bs[wn * 64 + nt * 16 + ln][q * 8];
#pragma unroll
        for (int mt = 0; mt < 4; mt++)
#pragma unroll
            for (int nt = 0; nt < 4; nt++)
                acc[mt][nt] = __builtin_amdgcn_mfma_f32_16x16x32_bf16(af[mt], bfr[nt], acc[mt][nt], 0, 0, 0);
    }

#pragma unroll
    for (int nt = 0; nt < 4; nt++) {
        int colg = i0 + wn * 64 + nt * 16 + ln;
        float bv = b1[e * I_DIM + colg];
        int coll = colg - chunk_base;
#pragma unroll
        for (int mt = 0; mt < 4; mt++)
#pragma unroll
            for (int r = 0; r < 4; r++) {
                int row = m0 + wm * 64 + mt * 16 + q * 4 + r;
                float v = acc[mt][nt][r] + bv;
                hmid[(size_t)row * chunkI + coll] = f2bf(gelu_fast(v));
            }
    }
}

// ---------------- pass 2: out[token] += pw * (hmid @ W2 + b2) ----------------
__global__ __launch_bounds__(256) void moe_gemm2(
    const __bf16* __restrict__ hmid, const __bf16* __restrict__ w2t,
    const float* __restrict__ b2, const int* __restrict__ off_g,
    const int* __restrict__ pair_token, const float* __restrict__ pair_w,
    float* __restrict__ out, int chunk_base, int chunkI)
{
    __shared__ __align__(16) __bf16 As[128][32];
    __shared__ __align__(16) __bf16 Bs[128][32];
    int m0 = blockIdx.x * 128;
    if (m0 >= off_g[E_NUM]) return;
    int e = 0;
#pragma unroll
    for (int k = 0; k < E_NUM - 1; k++) if (m0 >= off_g[k + 1]) e = k + 1;

    int tid = threadIdx.x;
    int w = tid >> 6, lane = tid & 63;
    int ln = lane & 15, q = lane >> 4;
    int wm = w >> 1, wn = w & 1;
    int sub = lane >> 2, kp = lane & 3;
    int h0 = blockIdx.y * 128;

    const __bf16* gA0 = hmid + (size_t)(m0 + w * 32 + sub) * chunkI + kp * 8;
    const __bf16* gA1 = gA0 + (size_t)16 * chunkI;
    const __bf16* gB0 = w2t + ((size_t)e * H_DIM + h0 + w * 32 + sub) * I_DIM + chunk_base + kp * 8;
    const __bf16* gB1 = gB0 + (size_t)16 * I_DIM;
    void* lA0 = &As[w * 32][0];
    void* lA1 = &As[w * 32 + 16][0];
    void* lB0 = &Bs[w * 32][0];
    void* lB1 = &Bs[w * 32 + 16][0];

    floatx4 acc[4][4];
#pragma unroll
    for (int a = 0; a < 4; a++)
#pragma unroll
        for (int b = 0; b < 4; b++) acc[a][b] = (floatx4){0.f, 0.f, 0.f, 0.f};

    for (int kk = 0; kk < chunkI; kk += 32) {
        __syncthreads();
        g2lds16(gA0 + kk, lA0);
        g2lds16(gA1 + kk, lA1);
        g2lds16(gB0 + kk, lB0);
        g2lds16(gB1 + kk, lB1);
        __syncthreads();
        bf16x8 af[4], bfr[4];
#pragma unroll
        for (int mt = 0; mt < 4; mt++) af[mt] = *(bf16x8*)&As[wm * 64 + mt * 16 + ln][q * 8];
#pragma unroll
        for (int nt = 0; nt < 4; nt++) bfr[nt] = *(bf16x8*)&Bs[wn * 64 + nt * 16 + ln][q * 8];
#pragma unroll
        for (int mt = 0; mt < 4; mt++)
#pragma unroll
            for (int nt = 0; nt < 4; nt++)
                acc[mt][nt] = __builtin_amdgcn_mfma_f32_16x16x32_bf16(af[mt], bfr[nt], acc[mt][nt], 0, 0, 0);
    }

    float bv[4];
#pragma unroll
    for (int nt = 0; nt < 4; nt++) bv[nt] = b2[e * H_DIM + h0 + wn * 64 + nt * 16 + ln];

#pragma unroll
    for (int mt = 0; mt < 4; mt++)
#pragma unroll
        for (int r = 0; r < 4; r++) {
            int row = m0 + wm * 64 + mt * 16 + q * 4 + r;
            int tok = pair_token[row];
            if (tok < 0) continue;
            float pw = pair_w[row];
            float* orow = out + (size_t)tok * H_DIM + h0 + wn * 64;
#pragma unroll
            for (int nt = 0; nt < 4; nt++) {
                float v = (acc[mt][nt][r] + bv[nt]) * pw;
                atomicAdd(orow + nt * 16 + ln, v);
            }
        }
}

extern "C" void kernel_launch(void* const* d_in, const int* in_sizes, int n_in,
                              void* d_out, int out_size, void* d_ws, size_t ws_size,
                              hipStream_t stream)
{
    const float* x  = (const float*)d_in[0];
    const float* gw = (const float*)d_in[1];
    const float* w1 = (const float*)d_in[2];
    const float* b1 = (const float*)d_in[3];
    const float* w2 = (const float*)d_in[4];
    const float* b2 = (const float*)d_in[5];
    float* out = (float*)d_out;
    float* logits = out + (size_t)T_TOK * H_DIM;

    // workspace carve
    char* p0 = (char*)d_ws;
    char* p = p0;
    int* cnt  = (int*)p; p += 32;
    int* fill = (int*)p; p += 32;
    int* off  = (int*)p; p += 64;
    int* tok_sel = (int*)p;  p += (size_t)2 * T_TOK * 4;
    float* tok_w = (float*)p; p += (size_t)2 * T_TOK * 4;
    int* pair_token = (int*)p;  p += (size_t)PADROWS * 4;
    float* pair_w   = (float*)p; p += (size_t)PADROWS * 4;
    p = (char*)(((uintptr_t)p + 255) & ~(uintptr_t)255);
    __bf16* xbf = (__bf16*)p; p += (size_t)T_TOK * H_DIM * 2;
    __bf16* w1t = (__bf16*)p; p += (size_t)E_NUM * H_DIM * I_DIM * 2;
    __bf16* w2t = (__bf16*)p; p += (size_t)E_NUM * H_DIM * I_DIM * 2;
    p = (char*)(((uintptr_t)p + 255) & ~(uintptr_t)255);
    __bf16* hmid = (__bf16*)p;
    size_t used = (size_t)(p - p0);
    size_t avail = (ws_size > used) ? ws_size - used : 0;

    static const int cands[] = {3072, 1536, 1024, 768, 512, 384, 256, 128};
    int chunkI = 128;
    for (int i = 0; i < 8; i++)
        if ((size_t)PADROWS * (size_t)cands[i] * 2 <= avail) { chunkI = cands[i]; break; }

    hipMemsetAsync(out, 0, (size_t)T_TOK * H_DIM * sizeof(float), stream);
    hipMemsetAsync(cnt, 0, 128, stream);
    hipMemsetAsync(pair_token, 0xFF, (size_t)PADROWS * 4, stream);

    convert_x<<<(T_TOK * H_DIM / 8) / 256, 256, 0, stream>>>(x, xbf);
    transpose_w<<<dim3(I_DIM / 64, H_DIM / 64, E_NUM), 256, 0, stream>>>(w1, w1t, H_DIM, I_DIM);
    transpose_w<<<dim3(H_DIM / 64, I_DIM / 64, E_NUM), 256, 0, stream>>>(w2, w2t, I_DIM, H_DIM);

    router_kernel<<<T_TOK / 256, 256, 0, stream>>>(x, gw, logits, tok_sel, tok_w, cnt);
    scan_kernel<<<1, 64, 0, stream>>>(cnt, off);
    scatter_kernel<<<T_TOK / 256, 256, 0, stream>>>(tok_sel, tok_w, off, fill,
                                                    pair_token, pair_w);

    for (int cb = 0; cb < I_DIM; cb += chunkI) {
        moe_gemm1<<<dim3(NTILE, chunkI / 128), 256, 0, stream>>>(
            xbf, w1t, b1, off, pair_token, hmid, cb, chunkI);
        moe_gemm2<<<dim3(NTILE, H_DIM / 128), 256, 0, stream>>>(
            hmid, w2t, b2, off, pair_token, pair_w, out, cb, chunkI);
    }
}

// Round 4
// 1493.794 us; speedup vs baseline: 2.0554x; 1.1370x over previous
//
#include <hip/hip_runtime.h>
#include <hip/hip_bf16.h>
#include <math.h>
#include <stdint.h>

#define T_TOK 32768
#define H_DIM 768
#define I_DIM 3072
#define E_NUM 8
#define PADROWS 66560              /* 2*T + 8*128, 128-aligned expert regions */
#define NTILE   520                /* PADROWS / 128 */

typedef __attribute__((ext_vector_type(8))) __bf16 bf16x8;
typedef __attribute__((ext_vector_type(4))) float floatx4;

__device__ inline __bf16 f2bf(float f) { return (__bf16)f; }
__device__ inline unsigned short f2bfu(float f) {
    __bf16 b = (__bf16)f; return *(unsigned short*)&b;
}
__device__ inline float bfu2f(unsigned short u) {
    union { unsigned v; float f; } c; c.v = ((unsigned)u) << 16; return c.f;
}

// async global->LDS, 16B/lane; LDS dest wave-uniform base (+lane*16),
// global address per-lane (gather-capable).
__device__ inline void g2lds16(const void* g, void* l) {
    __builtin_amdgcn_global_load_lds(
        (const __attribute__((address_space(1))) unsigned int*)g,
        (__attribute__((address_space(3))) unsigned int*)l, 16, 0, 0);
}

__device__ inline float gelu_fast(float x) {
    float x2 = x * x;
    float t = x * (0.7978845608f + 0.0356774081f * x2);
    float e = __expf(-2.f * t);
    return x / (1.f + e);
}

// ---------------- router ----------------
__global__ __launch_bounds__(256) void router_kernel(
    const float* __restrict__ x, const float* __restrict__ gw,
    float* __restrict__ logits, int* __restrict__ tok_sel,
    float* __restrict__ tok_w, int* __restrict__ cnt)
{
    __shared__ float sgw[E_NUM * H_DIM];
    __shared__ int lcnt[E_NUM];
    int tid = threadIdx.x;
    for (int i = tid; i < E_NUM * H_DIM; i += 256) sgw[i] = gw[i];
    if (tid < E_NUM) lcnt[tid] = 0;
    __syncthreads();

    int t = blockIdx.x * 256 + tid;
    const float* xr = x + (size_t)t * H_DIM;
    float acc[E_NUM];
#pragma unroll
    for (int e = 0; e < E_NUM; e++) acc[e] = 0.f;
    for (int k = 0; k < H_DIM; k += 4) {
        float4 xv = *(const float4*)(xr + k);
#pragma unroll
        for (int e = 0; e < E_NUM; e++) {
            const float* g = &sgw[e * H_DIM + k];
            acc[e] += xv.x * g[0] + xv.y * g[1] + xv.z * g[2] + xv.w * g[3];
        }
    }
#pragma unroll
    for (int e = 0; e < E_NUM; e++) logits[(size_t)t * E_NUM + e] = acc[e];

    int e1 = 0; float v1 = acc[0];
#pragma unroll
    for (int e = 1; e < E_NUM; e++) if (acc[e] > v1) { v1 = acc[e]; e1 = e; }
    int e2 = (e1 == 0) ? 1 : 0; float v2 = acc[(e1 == 0) ? 1 : 0];
#pragma unroll
    for (int e = 0; e < E_NUM; e++)
        if (e != e1 && acc[e] > v2) { v2 = acc[e]; e2 = e; }

    float p2 = expf(v2 - v1);
    float s = 1.f + p2;
    tok_sel[2 * t] = e1; tok_sel[2 * t + 1] = e2;
    tok_w[2 * t] = 1.f / s; tok_w[2 * t + 1] = p2 / s;

    atomicAdd(&lcnt[e1], 1); atomicAdd(&lcnt[e2], 1);
    __syncthreads();
    if (tid < E_NUM) atomicAdd(&cnt[tid], lcnt[tid]);
}

// ---------------- scan: 128-aligned expert offsets ----------------
__global__ void scan_kernel(const int* __restrict__ cnt, int* __restrict__ off)
{
    if (threadIdx.x == 0 && blockIdx.x == 0) {
        int o = 0;
        for (int e = 0; e < E_NUM; e++) {
            off[e] = o;
            o += (cnt[e] + 127) & ~127;
        }
        off[E_NUM] = o;
    }
}

// ---------------- scatter pairs; record token -> pair-slot map ----------------
__global__ __launch_bounds__(256) void scatter_kernel(
    const int* __restrict__ tok_sel, const float* __restrict__ tok_w,
    const int* __restrict__ off, int* __restrict__ fill,
    int* __restrict__ pair_token, float* __restrict__ pair_w,
    int* __restrict__ tok_pos)
{
    __shared__ int lcnt[E_NUM];
    __shared__ int base[E_NUM];
    int tid = threadIdx.x;
    if (tid < E_NUM) lcnt[tid] = 0;
    __syncthreads();
    int t = blockIdx.x * 256 + tid;
    int e1 = tok_sel[2 * t], e2 = tok_sel[2 * t + 1];
    int lp1 = atomicAdd(&lcnt[e1], 1);
    int lp2 = atomicAdd(&lcnt[e2], 1);
    __syncthreads();
    if (tid < E_NUM) base[tid] = (lcnt[tid] > 0) ? atomicAdd(&fill[tid], lcnt[tid]) : 0;
    __syncthreads();
    int p1 = off[e1] + base[e1] + lp1;
    int p2 = off[e2] + base[e2] + lp2;
    pair_token[p1] = t; pair_w[p1] = tok_w[2 * t];
    pair_token[p2] = t; pair_w[p2] = tok_w[2 * t + 1];
    tok_pos[2 * t] = p1; tok_pos[2 * t + 1] = p2;
}

// ---------------- x fp32 -> bf16 ----------------
__global__ __launch_bounds__(256) void convert_x(
    const float* __restrict__ x, __bf16* __restrict__ xb)
{
    int i = blockIdx.x * 256 + threadIdx.x;
    float4 a = ((const float4*)x)[2 * i];
    float4 b = ((const float4*)x)[2 * i + 1];
    bf16x8 o;
    o[0] = f2bf(a.x); o[1] = f2bf(a.y); o[2] = f2bf(a.z); o[3] = f2bf(a.w);
    o[4] = f2bf(b.x); o[5] = f2bf(b.y); o[6] = f2bf(b.z); o[7] = f2bf(b.w);
    ((bf16x8*)xb)[i] = o;
}

// ---------------- W (E,R,C) fp32 -> Wt (E,C,R) bf16 ----------------
__global__ __launch_bounds__(256) void transpose_w(
    const float* __restrict__ W, __bf16* __restrict__ Wt, int R, int C)
{
    __shared__ unsigned short T[64][66];
    int e = blockIdx.z;
    int r0 = blockIdx.y * 64, c0 = blockIdx.x * 64;
    const float* Wp = W + (size_t)e * R * C;
    __bf16* Wtp = Wt + (size_t)e * C * R;
    int tid = threadIdx.x;

    int rl = tid >> 2, cg = tid & 3;
    const float* src = Wp + (size_t)(r0 + rl) * C + c0 + cg * 16;
#pragma unroll
    for (int u = 0; u < 4; u++) {
        float4 v = *(const float4*)(src + u * 4);
        unsigned p0 = (unsigned)f2bfu(v.x) | ((unsigned)f2bfu(v.y) << 16);
        unsigned p1 = (unsigned)f2bfu(v.z) | ((unsigned)f2bfu(v.w) << 16);
        *(unsigned*)&T[rl][cg * 16 + u * 4]     = p0;
        *(unsigned*)&T[rl][cg * 16 + u * 4 + 2] = p1;
    }
    __syncthreads();

    int cl = tid >> 2, rg = tid & 3;
    __bf16* dst = Wtp + (size_t)(c0 + cl) * R + r0 + rg * 16;
#pragma unroll
    for (int half = 0; half < 2; half++) {
        bf16x8 o;
#pragma unroll
        for (int j = 0; j < 8; j++) {
            unsigned short b = T[rg * 16 + half * 8 + j][cl];
            o[j] = *(__bf16*)&b;
        }
        *(bf16x8*)(dst + half * 8) = o;
    }
}

// ---------------- pass 1: hmid = gelu(X @ W1 + b1)  (round-2 proven core) ----
// M-chunked: processes rows [r0, r0+mrows); hmid indexed by (row - r0).
__global__ __launch_bounds__(256) void moe_gemm1(
    const __bf16* __restrict__ xbf, const __bf16* __restrict__ w1t,
    const float* __restrict__ b1, const int* __restrict__ off_g,
    const int* __restrict__ pair_token, __bf16* __restrict__ hmid,
    int chunk_base, int chunkI, int r0)
{
    __shared__ __align__(16) __bf16 As[128][32];
    __shared__ __align__(16) __bf16 Bs[128][32];
    int m0 = r0 + blockIdx.x * 128;
    if (m0 >= off_g[E_NUM]) return;
    int e = 0;
#pragma unroll
    for (int k = 0; k < E_NUM - 1; k++) if (m0 >= off_g[k + 1]) e = k + 1;

    int tid = threadIdx.x;
    int w = tid >> 6, lane = tid & 63;
    int ln = lane & 15, q = lane >> 4;
    int wm = w >> 1, wn = w & 1;
    int sub = lane >> 2, kp = lane & 3;
    int i0 = chunk_base + blockIdx.y * 128;

    int rA0 = m0 + w * 32 + sub;
    int t0 = pair_token[rA0]; if (t0 < 0) t0 = 0;
    int t1 = pair_token[rA0 + 16]; if (t1 < 0) t1 = 0;
    const __bf16* gA0 = xbf + (size_t)t0 * H_DIM + kp * 8;
    const __bf16* gA1 = xbf + (size_t)t1 * H_DIM + kp * 8;
    const __bf16* gB0 = w1t + ((size_t)e * I_DIM + i0 + w * 32 + sub) * H_DIM + kp * 8;
    const __bf16* gB1 = gB0 + (size_t)16 * H_DIM;
    void* lA0 = &As[w * 32][0];
    void* lA1 = &As[w * 32 + 16][0];
    void* lB0 = &Bs[w * 32][0];
    void* lB1 = &Bs[w * 32 + 16][0];

    floatx4 acc[4][4];
#pragma unroll
    for (int a = 0; a < 4; a++)
#pragma unroll
        for (int b = 0; b < 4; b++) acc[a][b] = (floatx4){0.f, 0.f, 0.f, 0.f};

    for (int kk = 0; kk < H_DIM; kk += 32) {
        __syncthreads();
        g2lds16(gA0 + kk, lA0);
        g2lds16(gA1 + kk, lA1);
        g2lds16(gB0 + kk, lB0);
        g2lds16(gB1 + kk, lB1);
        __syncthreads();
        bf16x8 af[4], bfr[4];
#pragma unroll
        for (int mt = 0; mt < 4; mt++) af[mt] = *(bf16x8*)&As[wm * 64 + mt * 16 + ln][q * 8];
#pragma unroll
        for (int nt = 0; nt < 4; nt++) bfr[nt] = *(bf16x8*)&Bs[wn * 64 + nt * 16 + ln][q * 8];
#pragma unroll
        for (int mt = 0; mt < 4; mt++)
#pragma unroll
            for (int nt = 0; nt < 4; nt++)
                acc[mt][nt] = __builtin_amdgcn_mfma_f32_16x16x32_bf16(af[mt], bfr[nt], acc[mt][nt], 0, 0, 0);
    }

#pragma unroll
    for (int nt = 0; nt < 4; nt++) {
        int colg = i0 + wn * 64 + nt * 16 + ln;
        float bv = b1[e * I_DIM + colg];
        int coll = colg - chunk_base;
#pragma unroll
        for (int mt = 0; mt < 4; mt++)
#pragma unroll
            for (int r = 0; r < 4; r++) {
                int row = m0 + wm * 64 + mt * 16 + q * 4 + r;
                float v = acc[mt][nt][r] + bv;
                hmid[(size_t)(row - r0) * chunkI + coll] = f2bf(gelu_fast(v));
            }
    }
}

// ---------------- pass 2 (fused): y_pair[row] = hmid @ W2 (bf16, no atomics,
//                  no bias -- combine adds per-expert bias) ----------------
__global__ __launch_bounds__(256) void moe_gemm2_y(
    const __bf16* __restrict__ hmid, const __bf16* __restrict__ w2t,
    const int* __restrict__ off_g, __bf16* __restrict__ y_pair, int r0)
{
    __shared__ __align__(16) __bf16 As[128][32];
    __shared__ __align__(16) __bf16 Bs[128][32];
    int m0 = r0 + blockIdx.x * 128;
    if (m0 >= off_g[E_NUM]) return;
    int e = 0;
#pragma unroll
    for (int k = 0; k < E_NUM - 1; k++) if (m0 >= off_g[k + 1]) e = k + 1;

    int tid = threadIdx.x;
    int w = tid >> 6, lane = tid & 63;
    int ln = lane & 15, q = lane >> 4;
    int wm = w >> 1, wn = w & 1;
    int sub = lane >> 2, kp = lane & 3;
    int h0 = blockIdx.y * 128;

    const __bf16* gA0 = hmid + (size_t)(m0 - r0 + w * 32 + sub) * I_DIM + kp * 8;
    const __bf16* gA1 = gA0 + (size_t)16 * I_DIM;
    const __bf16* gB0 = w2t + ((size_t)e * H_DIM + h0 + w * 32 + sub) * I_DIM + kp * 8;
    const __bf16* gB1 = gB0 + (size_t)16 * I_DIM;
    void* lA0 = &As[w * 32][0];
    void* lA1 = &As[w * 32 + 16][0];
    void* lB0 = &Bs[w * 32][0];
    void* lB1 = &Bs[w * 32 + 16][0];

    floatx4 acc[4][4];
#pragma unroll
    for (int a = 0; a < 4; a++)
#pragma unroll
        for (int b = 0; b < 4; b++) acc[a][b] = (floatx4){0.f, 0.f, 0.f, 0.f};

    for (int kk = 0; kk < I_DIM; kk += 32) {
        __syncthreads();
        g2lds16(gA0 + kk, lA0);
        g2lds16(gA1 + kk, lA1);
        g2lds16(gB0 + kk, lB0);
        g2lds16(gB1 + kk, lB1);
        __syncthreads();
        bf16x8 af[4], bfr[4];
#pragma unroll
        for (int mt = 0; mt < 4; mt++) af[mt] = *(bf16x8*)&As[wm * 64 + mt * 16 + ln][q * 8];
#pragma unroll
        for (int nt = 0; nt < 4; nt++) bfr[nt] = *(bf16x8*)&Bs[wn * 64 + nt * 16 + ln][q * 8];
#pragma unroll
        for (int mt = 0; mt < 4; mt++)
#pragma unroll
            for (int nt = 0; nt < 4; nt++)
                acc[mt][nt] = __builtin_amdgcn_mfma_f32_16x16x32_bf16(af[mt], bfr[nt], acc[mt][nt], 0, 0, 0);
    }

#pragma unroll
    for (int mt = 0; mt < 4; mt++)
#pragma unroll
        for (int r = 0; r < 4; r++) {
            int row = m0 + wm * 64 + mt * 16 + q * 4 + r;
            __bf16* yrow = y_pair + (size_t)row * H_DIM + h0 + wn * 64;
#pragma unroll
            for (int nt = 0; nt < 4; nt++)
                yrow[nt * 16 + ln] = f2bf(acc[mt][nt][r]);
        }
}

// ---------------- combine: out[t] = w1*(y[p1]+b2[e1]) + w2*(y[p2]+b2[e2]) ----
__global__ __launch_bounds__(256) void combine_kernel(
    const __bf16* __restrict__ y_pair, const int* __restrict__ tok_pos,
    const int* __restrict__ tok_sel, const float* __restrict__ tok_w,
    const float* __restrict__ b2, float* __restrict__ out)
{
    int g = blockIdx.x * 256 + threadIdx.x;
    int t = g / 192;
    int u = g - t * 192;
    int p1 = tok_pos[2 * t], p2 = tok_pos[2 * t + 1];
    int e1 = tok_sel[2 * t], e2 = tok_sel[2 * t + 1];
    float w1 = tok_w[2 * t], w2 = tok_w[2 * t + 1];
    ushort4 a = *(const ushort4*)(y_pair + (size_t)p1 * H_DIM + u * 4);
    ushort4 b = *(const ushort4*)(y_pair + (size_t)p2 * H_DIM + u * 4);
    float4 ba = *(const float4*)(b2 + e1 * H_DIM + u * 4);
    float4 bb = *(const float4*)(b2 + e2 * H_DIM + u * 4);
    float4 o;
    o.x = w1 * (bfu2f(a.x) + ba.x) + w2 * (bfu2f(b.x) + bb.x);
    o.y = w1 * (bfu2f(a.y) + ba.y) + w2 * (bfu2f(b.y) + bb.y);
    o.z = w1 * (bfu2f(a.z) + ba.z) + w2 * (bfu2f(b.z) + bb.z);
    o.w = w1 * (bfu2f(a.w) + ba.w) + w2 * (bfu2f(b.w) + bb.w);
    *(float4*)(out + (size_t)t * H_DIM + u * 4) = o;
}

// ---------------- pass 2 (fallback): atomic accumulate (round-2 core) -------
__global__ __launch_bounds__(256) void moe_gemm2_atomic(
    const __bf16* __restrict__ hmid, const __bf16* __restrict__ w2t,
    const float* __restrict__ b2, const int* __restrict__ off_g,
    const int* __restrict__ pair_token, const float* __restrict__ pair_w,
    float* __restrict__ out, int chunk_base, int chunkI)
{
    __shared__ __align__(16) __bf16 As[128][32];
    __shared__ __align__(16) __bf16 Bs[128][32];
    int m0 = blockIdx.x * 128;
    if (m0 >= off_g[E_NUM]) return;
    int e = 0;
#pragma unroll
    for (int k = 0; k < E_NUM - 1; k++) if (m0 >= off_g[k + 1]) e = k + 1;

    int tid = threadIdx.x;
    int w = tid >> 6, lane = tid & 63;
    int ln = lane & 15, q = lane >> 4;
    int wm = w >> 1, wn = w & 1;
    int sub = lane >> 2, kp = lane & 3;
    int h0 = blockIdx.y * 128;

    const __bf16* gA0 = hmid + (size_t)(m0 + w * 32 + sub) * chunkI + kp * 8;
    const __bf16* gA1 = gA0 + (size_t)16 * chunkI;
    const __bf16* gB0 = w2t + ((size_t)e * H_DIM + h0 + w * 32 + sub) * I_DIM + chunk_base + kp * 8;
    const __bf16* gB1 = gB0 + (size_t)16 * I_DIM;
    void* lA0 = &As[w * 32][0];
    void* lA1 = &As[w * 32 + 16][0];
    void* lB0 = &Bs[w * 32][0];
    void* lB1 = &Bs[w * 32 + 16][0];

    floatx4 acc[4][4];
#pragma unroll
    for (int a = 0; a < 4; a++)
#pragma unroll
        for (int b = 0; b < 4; b++) acc[a][b] = (floatx4){0.f, 0.f, 0.f, 0.f};

    for (int kk = 0; kk < chunkI; kk += 32) {
        __syncthreads();
        g2lds16(gA0 + kk, lA0);
        g2lds16(gA1 + kk, lA1);
        g2lds16(gB0 + kk, lB0);
        g2lds16(gB1 + kk, lB1);
        __syncthreads();
        bf16x8 af[4], bfr[4];
#pragma unroll
        for (int mt = 0; mt < 4; mt++) af[mt] = *(bf16x8*)&As[wm * 64 + mt * 16 + ln][q * 8];
#pragma unroll
        for (int nt = 0; nt < 4; nt++) bfr[nt] = *(bf16x8*)&Bs[wn * 64 + nt * 16 + ln][q * 8];
#pragma unroll
        for (int mt = 0; mt < 4; mt++)
#pragma unroll
            for (int nt = 0; nt < 4; nt++)
                acc[mt][nt] = __builtin_amdgcn_mfma_f32_16x16x32_bf16(af[mt], bfr[nt], acc[mt][nt], 0, 0, 0);
    }

    float bscale = (chunk_base == 0) ? 1.f : 0.f;   // bias exactly once
    float bv[4];
#pragma unroll
    for (int nt = 0; nt < 4; nt++) bv[nt] = bscale * b2[e * H_DIM + h0 + wn * 64 + nt * 16 + ln];

#pragma unroll
    for (int mt = 0; mt < 4; mt++)
#pragma unroll
        for (int r = 0; r < 4; r++) {
            int row = m0 + wm * 64 + mt * 16 + q * 4 + r;
            int tok = pair_token[row];
            if (tok < 0) continue;
            float pw = pair_w[row];
            float* orow = out + (size_t)tok * H_DIM + h0 + wn * 64;
#pragma unroll
            for (int nt = 0; nt < 4; nt++) {
                float v = (acc[mt][nt][r] + bv[nt]) * pw;
                atomicAdd(orow + nt * 16 + ln, v);
            }
        }
}

extern "C" void kernel_launch(void* const* d_in, const int* in_sizes, int n_in,
                              void* d_out, int out_size, void* d_ws, size_t ws_size,
                              hipStream_t stream)
{
    const float* x  = (const float*)d_in[0];
    const float* gw = (const float*)d_in[1];
    const float* w1 = (const float*)d_in[2];
    const float* b1 = (const float*)d_in[3];
    const float* w2 = (const float*)d_in[4];
    const float* b2 = (const float*)d_in[5];
    float* out = (float*)d_out;
    float* logits = out + (size_t)T_TOK * H_DIM;

    const size_t XBF_SZ = (size_t)T_TOK * H_DIM * 2;           // 50.3 MB
    const size_t W1T_SZ = (size_t)E_NUM * H_DIM * I_DIM * 2;   // 37.75 MB
    const size_t W2T_SZ = W1T_SZ;
    const size_t YP_SZ  = (size_t)PADROWS * H_DIM * 2;         // 102.2 MB

    // small bookkeeping
    char* p0 = (char*)d_ws;
    char* p = p0;
    int* cnt  = (int*)p; p += 32;
    int* fill = (int*)p; p += 32;
    int* off  = (int*)p; p += 64;
    int* tok_sel = (int*)p;  p += (size_t)2 * T_TOK * 4;
    float* tok_w = (float*)p; p += (size_t)2 * T_TOK * 4;
    int* tok_pos = (int*)p;  p += (size_t)2 * T_TOK * 4;
    int* pair_token = (int*)p;  p += (size_t)PADROWS * 4;
    float* pair_w   = (float*)p; p += (size_t)PADROWS * 4;
    p = (char*)(((uintptr_t)p + 255) & ~(uintptr_t)255);

    __bf16* xbf = (__bf16*)p;
    __bf16* w1t = (__bf16*)(p + XBF_SZ);
    __bf16* w2t = (__bf16*)(p + XBF_SZ + W1T_SZ);
    char* after_w = p + XBF_SZ + W1T_SZ + W2T_SZ;

    // fused path: + y_pair + M-chunked full-I hmid
    size_t base_fused = (size_t)(after_w - p0) + YP_SZ;
    long long avail_f = (long long)ws_size - (long long)base_fused;
    int mrows = 0;
    if (avail_f >= (long long)128 * I_DIM * 2) {
        long long r = avail_f / ((long long)I_DIM * 2);
        if (r > PADROWS) r = PADROWS;
        mrows = (int)(r & ~127LL);
    }
    bool fused = (mrows >= 128);

    hipMemsetAsync(cnt, 0, 128, stream);
    hipMemsetAsync(pair_token, 0xFF, (size_t)PADROWS * 4, stream);

    router_kernel<<<T_TOK / 256, 256, 0, stream>>>(x, gw, logits, tok_sel, tok_w, cnt);
    scan_kernel<<<1, 64, 0, stream>>>(cnt, off);
    scatter_kernel<<<T_TOK / 256, 256, 0, stream>>>(tok_sel, tok_w, off, fill,
                                                    pair_token, pair_w, tok_pos);

    convert_x<<<(T_TOK * H_DIM / 8) / 256, 256, 0, stream>>>(x, xbf);
    transpose_w<<<dim3(I_DIM / 64, H_DIM / 64, E_NUM), 256, 0, stream>>>(w1, w1t, H_DIM, I_DIM);
    transpose_w<<<dim3(H_DIM / 64, I_DIM / 64, E_NUM), 256, 0, stream>>>(w2, w2t, I_DIM, H_DIM);

    if (fused) {
        __bf16* y_pair = (__bf16*)after_w;
        __bf16* hmid = (__bf16*)(after_w + YP_SZ);

        for (int r0 = 0; r0 < PADROWS; r0 += mrows) {
            int rows = PADROWS - r0; if (rows > mrows) rows = mrows;
            int xt = rows / 128;
            moe_gemm1<<<dim3(xt, I_DIM / 128), 256, 0, stream>>>(
                xbf, w1t, b1, off, pair_token, hmid, 0, I_DIM, r0);
            moe_gemm2_y<<<dim3(xt, H_DIM / 128), 256, 0, stream>>>(
                hmid, w2t, off, y_pair, r0);
        }
        combine_kernel<<<(T_TOK * 192) / 256, 256, 0, stream>>>(
            y_pair, tok_pos, tok_sel, tok_w, b2, out);
    } else {
        // I-chunked atomic fallback (round-2 structure)
        char* hm = after_w;
        size_t avail = (ws_size > (size_t)(hm - p0)) ? ws_size - (size_t)(hm - p0) : 0;
        static const int cands[] = {3072, 1536, 1024, 768, 512, 384, 256, 128};
        int chunkI = 128;
        for (int i = 0; i < 8; i++)
            if ((size_t)PADROWS * (size_t)cands[i] * 2 <= avail) { chunkI = cands[i]; break; }
        __bf16* hmid = (__bf16*)hm;

        hipMemsetAsync(out, 0, (size_t)T_TOK * H_DIM * sizeof(float), stream);
        for (int cb = 0; cb < I_DIM; cb += chunkI) {
            moe_gemm1<<<dim3(NTILE, chunkI / 128), 256, 0, stream>>>(
                xbf, w1t, b1, off, pair_token, hmid, cb, chunkI, 0);
            moe_gemm2_atomic<<<dim3(NTILE, H_DIM / 128), 256, 0, stream>>>(
                hmid, w2t, b2, off, pair_token, pair_w, out, cb, chunkI);
        }
    }
}